// Round 1
// baseline (49.890 us; speedup 1.0000x reference)
//
#include <hip/hip_runtime.h>

#define S_LEN 4096
#define Dh 64
#define BQ 128
#define BK 64
#define THREADS 256

typedef __attribute__((ext_vector_type(8))) short bf16x8;
typedef __attribute__((ext_vector_type(4))) float f32x4;

__device__ __forceinline__ short f2bf(float f) {
    union { float f; unsigned u; } c; c.f = f;
    unsigned u = c.u + 0x7FFFu + ((c.u >> 16) & 1u);
    return (short)(u >> 16);
}

__global__ __launch_bounds__(THREADS, 2) void swin_attn(
    const float* __restrict__ q, const float* __restrict__ k,
    const float* __restrict__ qr, const float* __restrict__ kr,
    const float* __restrict__ v, const int* __restrict__ hor,
    float* __restrict__ out)
{
    const int W = hor[0];
    const int q0 = blockIdx.x * BQ;
    const int bh = blockIdx.y;
    const size_t base = (size_t)bh * S_LEN * Dh;

    const int tid = threadIdx.x;
    const int lane = tid & 63;
    const int wv = tid >> 6;
    const int g = lane >> 4;      // 0..3
    const int l16 = lane & 15;    // 0..15

    // LDS: K(concat) [64 keys][128 feats] bf16 swizzled; Vt [64 e][64 keys] bf16 swizzled;
    // S per-wave [32 q][64 keys] bf16 swizzled.
    __shared__ __align__(16) char sK[BK * 256];
    __shared__ __align__(16) char sV[64 * 128];
    __shared__ __align__(16) char sS[4][32 * 128];

    // ---- Load Q fragments from global (A-layout: row=l16, k=g*8+j), feat concat q||qr
    bf16x8 qf[2][4];
    #pragma unroll
    for (int rb = 0; rb < 2; ++rb) {
        int qg = q0 + wv * 32 + rb * 16 + l16;
        const float* qrow  = q  + base + (size_t)qg * Dh;
        const float* qrrow = qr + base + (size_t)qg * Dh;
        #pragma unroll
        for (int fb = 0; fb < 4; ++fb) {
            int feat = fb * 32 + g * 8;
            const float* src = (feat < 64) ? (qrow + feat) : (qrrow + (feat - 64));
            f32x4 a = *(const f32x4*)src;
            f32x4 b = *(const f32x4*)(src + 4);
            bf16x8 fr;
            #pragma unroll
            for (int j = 0; j < 4; ++j) { fr[j] = f2bf(a[j]); fr[4 + j] = f2bf(b[j]); }
            qf[rb][fb] = fr;
        }
    }

    f32x4 nacc[2][4];
    f32x4 dacc[2];
    #pragma unroll
    for (int rb = 0; rb < 2; ++rb) {
        dacc[rb] = (f32x4){0.f, 0.f, 0.f, 0.f};
        #pragma unroll
        for (int eb = 0; eb < 4; ++eb) nacc[rb][eb] = (f32x4){0.f, 0.f, 0.f, 0.f};
    }
    bf16x8 ones;
    #pragma unroll
    for (int j = 0; j < 8; ++j) ones[j] = (short)0x3F80;  // bf16 1.0

    const int lo_key = q0 - (W - 1);
    const int kt_lo = (lo_key <= 0) ? 0 : (lo_key >> 6);
    const int kt_hi = (q0 + BQ - 1) >> 6;

    for (int kt = kt_lo; kt <= kt_hi; ++kt) {
        const int k0 = kt << 6;
        __syncthreads();  // protect LDS reuse from previous tile's readers

        // ---- stage K||Kr tile: [64][128] bf16, 16B chunks, XOR swizzle ((row&7)<<4)
        #pragma unroll
        for (int i = 0; i < 4; ++i) {
            int c = tid + THREADS * i;      // 1024 chunks of 8 feats
            int row = c >> 4;
            int f0 = (c & 15) * 8;
            const float* src = (f0 < 64) ? (k  + base + (size_t)(k0 + row) * Dh + f0)
                                         : (kr + base + (size_t)(k0 + row) * Dh + (f0 - 64));
            f32x4 a = *(const f32x4*)src;
            f32x4 b = *(const f32x4*)(src + 4);
            bf16x8 w8;
            #pragma unroll
            for (int j = 0; j < 4; ++j) { w8[j] = f2bf(a[j]); w8[4 + j] = f2bf(b[j]); }
            int off = row * 256 + ((f0 * 2) ^ ((row & 7) << 4));
            *(bf16x8*)(sK + off) = w8;
        }
        // ---- stage V transposed: Vt[e][key] bf16, XOR swizzle ((e&7)<<4)
        #pragma unroll
        for (int i = 0; i < 4; ++i) {
            int c = tid + THREADS * i;      // 1024 float4
            int row = c >> 4;               // key
            int c4 = (c & 15) * 4;          // e base
            f32x4 a = *(const f32x4*)(v + base + (size_t)(k0 + row) * Dh + c4);
            #pragma unroll
            for (int j = 0; j < 4; ++j) {
                int e = c4 + j;
                int off = e * 128 + ((row * 2) ^ ((e & 7) << 4));
                *(short*)(sV + off) = f2bf(a[j]);
            }
        }
        __syncthreads();

        const bool dense = (k0 + BK - 1 <= q0) && (k0 >= q0 + BQ - 1 - (W - 1));

        // ---- QK^T (K=128) -> mask -> write S to wave-private LDS (bf16, swizzled)
        #pragma unroll
        for (int kb = 0; kb < 4; ++kb) {
            bf16x8 kf[4];
            const int key = kb * 16 + l16;
            const int rowoff = key * 256;
            const int sw = (key & 7) << 4;
            #pragma unroll
            for (int fb = 0; fb < 4; ++fb)
                kf[fb] = *(const bf16x8*)(sK + rowoff + ((fb * 64 + g * 16) ^ sw));
            #pragma unroll
            for (int rb = 0; rb < 2; ++rb) {
                f32x4 s = {0.f, 0.f, 0.f, 0.f};
                #pragma unroll
                for (int fb = 0; fb < 4; ++fb)
                    s = __builtin_amdgcn_mfma_f32_16x16x32_bf16(qf[rb][fb], kf[fb], s, 0, 0, 0);
                const int qrow0 = rb * 16 + g * 4;            // in-wave q row
                const int qg0 = q0 + wv * 32 + qrow0;         // global q
                const int mg = k0 + kb * 16 + l16;            // global key
                if (!dense) {
                    #pragma unroll
                    for (int r = 0; r < 4; ++r) {
                        unsigned d = (unsigned)(qg0 + r - mg);
                        if (d >= (unsigned)W) s[r] = 0.f;
                    }
                }
                #pragma unroll
                for (int r = 0; r < 4; ++r) {
                    int row = qrow0 + r;
                    int off = row * 128 + (((kb * 16 + l16) * 2) ^ ((row & 7) << 4));
                    *(short*)(sS[wv] + off) = f2bf(s[r]);
                }
            }
        }

        // ---- PV (K-dim = 64 keys) + denominator via ones-B MFMA
        #pragma unroll
        for (int kb2 = 0; kb2 < 2; ++kb2) {
            bf16x8 af[2];
            #pragma unroll
            for (int rb = 0; rb < 2; ++rb) {
                int row = rb * 16 + l16;
                int off = row * 128 + ((kb2 * 64 + g * 16) ^ ((row & 7) << 4));
                af[rb] = *(const bf16x8*)(sS[wv] + off);
            }
            #pragma unroll
            for (int rb = 0; rb < 2; ++rb)
                dacc[rb] = __builtin_amdgcn_mfma_f32_16x16x32_bf16(af[rb], ones, dacc[rb], 0, 0, 0);
            #pragma unroll
            for (int eb = 0; eb < 4; ++eb) {
                int e = eb * 16 + l16;
                int off = e * 128 + ((kb2 * 64 + g * 16) ^ ((e & 7) << 4));
                bf16x8 bfr = *(const bf16x8*)(sV + off);
                #pragma unroll
                for (int rb = 0; rb < 2; ++rb)
                    nacc[rb][eb] = __builtin_amdgcn_mfma_f32_16x16x32_bf16(af[rb], bfr, nacc[rb][eb], 0, 0, 0);
            }
        }
    }

    // ---- epilogue: out = N / (D + eps); D is row-aligned with N (ones-B trick)
    #pragma unroll
    for (int rb = 0; rb < 2; ++rb) {
        f32x4 rc;
        #pragma unroll
        for (int r = 0; r < 4; ++r) rc[r] = 1.0f / (dacc[rb][r] + 1e-12f);
        const int qg0 = q0 + wv * 32 + rb * 16 + g * 4;
        #pragma unroll
        for (int eb = 0; eb < 4; ++eb) {
            #pragma unroll
            for (int r = 0; r < 4; ++r) {
                out[base + (size_t)(qg0 + r) * Dh + eb * 16 + l16] = nacc[rb][eb][r] * rc[r];
            }
        }
    }
}

extern "C" void kernel_launch(void* const* d_in, const int* in_sizes, int n_in,
                              void* d_out, int out_size, void* d_ws, size_t ws_size,
                              hipStream_t stream) {
    const float* q  = (const float*)d_in[0];
    const float* k  = (const float*)d_in[1];
    const float* qr = (const float*)d_in[2];
    const float* kr = (const float*)d_in[3];
    const float* v  = (const float*)d_in[4];
    const int* hor  = (const int*)d_in[5];
    float* out = (float*)d_out;

    const int BH = in_sizes[0] / (S_LEN * Dh);   // B*H = 16
    dim3 grid(S_LEN / BQ, BH);
    hipLaunchKernelGGL(swin_attn, grid, dim3(THREADS), 0, stream,
                       q, k, qr, kr, v, hor, out);
}